// Round 1
// baseline (10184.326 us; speedup 1.0000x reference)
//
#include <hip/hip_runtime.h>
#include <hip/hip_bf16.h>
#include <stdint.h>

typedef unsigned short u16;
typedef unsigned int   u32;
typedef unsigned long long u64;

typedef __attribute__((ext_vector_type(4))) float  f32x4;
typedef __attribute__((ext_vector_type(8))) short  bf16x8;
typedef __attribute__((ext_vector_type(8))) unsigned short us8;

#define T_LEN 2048
#define BATCH 32
#define IDIM  512
#define HDIM  512
#define G4    2048

// workspace layout (bytes)
#define XBF_OFF   0ull            // bf16 x            : 33554432 u16 (67108864 B)
#define WIH_OFF   67108864ull     // bf16 wih[2][2048][512]
#define WHH_OFF   71303168ull     // bf16 whh[2][2048][512]
#define XP_OFF    75497472ull     // bf16 xp[2][T][64][1024] (scan-friendly permuted layout)
#define HBUF_OFF  612368384ull    // bf16 hbuf[2][2 slots][32][512]
#define FLG_OFF   612499456ull    // u32 flags[2][64]
#define WS_NEED   612499968ull

__device__ __forceinline__ u16 f2bf(float f) {
  u32 u = __float_as_uint(f);
  return (u16)((u + 0x7FFFu + ((u >> 16) & 1u)) >> 16);   // RTNE
}
__device__ __forceinline__ float bf2f(u16 h) {
  return __uint_as_float(((u32)h) << 16);
}
__device__ __forceinline__ float sigm(float x) {
  x = fminf(fmaxf(x, -30.f), 30.f);
  return 1.f / (1.f + __expf(-x));
}
__device__ __forceinline__ float tanh_(float x) {
  x = fminf(fmaxf(x, -15.f), 15.f);
  float e = __expf(2.f * x);
  return (e - 1.f) / (e + 1.f);
}

// ---------------- prep: fp32 -> bf16 conversions + h0 seed + flag reset ----------------
__global__ __launch_bounds__(256) void prep_kernel(
    const float4* __restrict__ x,
    const float4* __restrict__ wihf, const float4* __restrict__ wihb,
    const float4* __restrict__ whhf, const float4* __restrict__ whhb,
    const float4* __restrict__ h0f,  const float4* __restrict__ h0b,
    ushort4* __restrict__ xbf, ushort4* __restrict__ wihbf,
    ushort4* __restrict__ whhbf, ushort4* __restrict__ hbuf,
    u32* __restrict__ flags)
{
  if (blockIdx.x == 0 && threadIdx.x < 128) flags[threadIdx.x] = 0;
  const size_t NX = 8388608, NW = 262144, NH = 4096;   // float4 units
  const size_t total = NX + 4 * NW + 2 * NH;
  size_t stride = (size_t)gridDim.x * blockDim.x;
  for (size_t i = (size_t)blockIdx.x * blockDim.x + threadIdx.x; i < total; i += stride) {
    const float4* src; ushort4* dst; size_t off;
    if (i < NX)                { src = x;    dst = xbf;          off = i; }
    else if (i < NX + NW)      { src = wihf; dst = wihbf;        off = i - NX; }
    else if (i < NX + 2 * NW)  { src = wihb; dst = wihbf + NW;   off = i - NX - NW; }
    else if (i < NX + 3 * NW)  { src = whhf; dst = whhbf;        off = i - NX - 2 * NW; }
    else if (i < NX + 4 * NW)  { src = whhb; dst = whhbf + NW;   off = i - NX - 3 * NW; }
    else if (i < NX + 4 * NW + NH) { src = h0f; dst = hbuf;        off = i - NX - 4 * NW; }
    else                       { src = h0b; dst = hbuf + 8192;   off = i - NX - 4 * NW - NH; }
    float4 v = src[off];
    ushort4 o;
    o.x = f2bf(v.x); o.y = f2bf(v.y); o.z = f2bf(v.z); o.w = f2bf(v.w);
    dst[off] = o;
  }
}

// ---------------- x-projection GEMM: xp = x @ Wih^T + b (both dirs), permuted store --------
// M=65536 (t*32+b), N=2048 (g*512 + w*8 + jj), K=512. 128x128 tile, 4 waves, bf16 MFMA.
__global__ __launch_bounds__(256, 2) void gemm_xp(
    const u16* __restrict__ xbf, const u16* __restrict__ wihbf,
    const float* __restrict__ bias_f, const float* __restrict__ bias_b,
    u16* __restrict__ xpo)
{
  const int m0 = blockIdx.x * 128;
  const int n0 = blockIdx.y * 128;
  const int dir = blockIdx.z;
  const int tid = threadIdx.x, l = tid & 63, wv = tid >> 6;

  __shared__ u16 As[128 * 72];   // padded rows (+8 bf16) to break bank conflicts
  __shared__ u16 Bs[128 * 72];

  const u16* wih = wihbf + (size_t)dir * G4 * IDIM;

  f32x4 acc[4][4];
#pragma unroll
  for (int i = 0; i < 4; i++)
#pragma unroll
    for (int j = 0; j < 4; j++) acc[i][j] = (f32x4){0.f, 0.f, 0.f, 0.f};

  const int srow = tid >> 1, shalf = tid & 1;
  const int wr = wv >> 1, wc = wv & 1;

  for (int k0 = 0; k0 < IDIM; k0 += 64) {
    __syncthreads();
    {
      const u16* ag = xbf + (size_t)(m0 + srow) * IDIM + k0 + shalf * 32;
      const u16* bg = wih + (size_t)(n0 + srow) * IDIM + k0 + shalf * 32;
      u16* ad = &As[srow * 72 + shalf * 32];
      u16* bd = &Bs[srow * 72 + shalf * 32];
#pragma unroll
      for (int q = 0; q < 4; q++) *(us8*)(ad + q * 8) = *(const us8*)(ag + q * 8);
#pragma unroll
      for (int q = 0; q < 4; q++) *(us8*)(bd + q * 8) = *(const us8*)(bg + q * 8);
    }
    __syncthreads();
#pragma unroll
    for (int kk = 0; kk < 2; kk++) {
      bf16x8 af[4], bv[4];
#pragma unroll
      for (int i = 0; i < 4; i++)
        af[i] = *(const bf16x8*)&As[(wr * 64 + i * 16 + (l & 15)) * 72 + kk * 32 + (l >> 4) * 8];
#pragma unroll
      for (int j = 0; j < 4; j++)
        bv[j] = *(const bf16x8*)&Bs[(wc * 64 + j * 16 + (l & 15)) * 72 + kk * 32 + (l >> 4) * 8];
#pragma unroll
      for (int i = 0; i < 4; i++)
#pragma unroll
        for (int j = 0; j < 4; j++)
          acc[i][j] = __builtin_amdgcn_mfma_f32_16x16x32_bf16(af[i], bv[j], acc[i][j], 0, 0, 0);
    }
  }

  const float* bias = dir ? bias_b : bias_f;
  const size_t dirbase = (size_t)dir * T_LEN * 65536ull;
#pragma unroll
  for (int j = 0; j < 4; j++) {
    int col = n0 + wc * 64 + j * 16 + (l & 15);
    float bb = bias[col];
    size_t coloff = (size_t)((col >> 3) & 63) * 1024 + (size_t)(col >> 9) * 8 + (size_t)(col & 7);
#pragma unroll
    for (int i = 0; i < 4; i++) {
#pragma unroll
      for (int r = 0; r < 4; r++) {
        int row = m0 + wr * 64 + i * 16 + (l >> 4) * 4 + r;
        int t = row >> 5, b = row & 31;
        xpo[dirbase + (size_t)t * 65536 + coloff + (size_t)b * 32] = f2bf(acc[i][j][r] + bb);
      }
    }
  }
}

// ---------------- persistent recurrent scan --------------------------------------------
// 128 WGs: dir = bid>>6, w = bid&63. WG owns hidden units j = w*8 .. w*8+7, all 32 batches.
// Per step: gates[32, 32] = h_prev[32,512] @ WhhRows^T, via 16x16x32 MFMA,
// waves = (mt = batch-half, kh = K-half); cross-wave K reduction through LDS.
// h broadcast via agent-scope atomics + per-WG flag (release: vmcnt drain before flag).
__global__ __launch_bounds__(256) void lstm_scan(
    const u16* __restrict__ xp, const u16* __restrict__ whhbf,
    const float* __restrict__ c0f, const float* __restrict__ c0b,
    u16* hbuf, u32* flags, float* __restrict__ out)
{
  const int bid = blockIdx.x;
  const int dir = bid >> 6;
  const int w   = bid & 63;
  const int tid = threadIdx.x, l = tid & 63, wv = tid >> 6;
  const int mt = wv >> 1, kh = wv & 1;

  __shared__ u16 Wl[32][520];       // 32 Whh rows (n = g*8+jj), padded
  __shared__ float Gl[2][32][33];   // per-K-half partial gates
  __shared__ ushort4 Xs[256];       // xp_t slice (bf16) [b][n]
  __shared__ u64 Htmp[64];          // new h slice (bf16) packed

  {
    int n = tid >> 3, part = tid & 7;
    int g = n >> 3, jj = n & 7;
    const u16* src = whhbf + ((size_t)dir * G4 + (size_t)g * 512 + w * 8 + jj) * 512 + part * 64;
    u16* dst = &Wl[n][part * 64];
#pragma unroll
    for (int q = 0; q < 8; q++) *(us8*)(dst + q * 8) = *(const us8*)(src + q * 8);
  }
  __syncthreads();

  // hoist weight fragments into registers: bfr[nt][kk], this wave's K-half
  bf16x8 bfr[2][8];
#pragma unroll
  for (int nt = 0; nt < 2; nt++)
#pragma unroll
    for (int kk = 0; kk < 8; kk++)
      bfr[nt][kk] = *(const bf16x8*)&Wl[nt * 16 + (l & 15)][kh * 256 + kk * 32 + (l >> 4) * 8];

  const int b_ = tid >> 3, jj_ = tid & 7;   // this thread's (batch, local hidden)
  const float* c0 = dir ? c0b : c0f;
  float c = c0[b_ * 512 + w * 8 + jj_];

  u16* hb = hbuf + (size_t)dir * 2 * BATCH * HDIM;
  u32* flg = flags + dir * 64;
  const u16* xpd = xp + (size_t)dir * T_LEN * 65536ull;
  const u16* xsf = (const u16*)Xs;
  const int arow = mt * 16 + (l & 15);

  for (int k = 1; k <= T_LEN + 1; k++) {
    const bool compute = (k <= T_LEN);
    ushort4 myxp = {0, 0, 0, 0};
    if (compute) {
      int t = dir ? (T_LEN - k) : (k - 1);
      myxp = *(const ushort4*)(xpd + ((size_t)t * 64 + w) * 1024 + tid * 4);  // prefetch
    }
    if (wv == 0) {
      const u32 need = (u32)(k - 1);
      for (;;) {
        u32 v = __hip_atomic_load(flg + l, __ATOMIC_RELAXED, __HIP_MEMORY_SCOPE_AGENT);
        if (!__any(v < need)) break;
        __builtin_amdgcn_s_sleep(2);
      }
    }
    __syncthreads();                                   // barrier 1: h_{k-1} visible
    const int prev = (k - 1) & 1;
    const u16* hsrc = hb + prev * (BATCH * HDIM);

    if (compute) {
      f32x4 acc0 = {0.f, 0.f, 0.f, 0.f}, acc1 = {0.f, 0.f, 0.f, 0.f};
      const u64* hrow = (const u64*)(hsrc + (size_t)arow * 512);
      bf16x8 afr[8];
#pragma unroll
      for (int kk = 0; kk < 8; kk++) {                 // issue all loads first
        u64 qlo = __hip_atomic_load(hrow + kh * 64 + kk * 8 + (l >> 4) * 2,
                                    __ATOMIC_RELAXED, __HIP_MEMORY_SCOPE_AGENT);
        u64 qhi = __hip_atomic_load(hrow + kh * 64 + kk * 8 + (l >> 4) * 2 + 1,
                                    __ATOMIC_RELAXED, __HIP_MEMORY_SCOPE_AGENT);
        union { u64 q[2]; bf16x8 v; } uu;
        uu.q[0] = qlo; uu.q[1] = qhi;
        afr[kk] = uu.v;
      }
#pragma unroll
      for (int kk = 0; kk < 8; kk++) {
        acc0 = __builtin_amdgcn_mfma_f32_16x16x32_bf16(afr[kk], bfr[0][kk], acc0, 0, 0, 0);
        acc1 = __builtin_amdgcn_mfma_f32_16x16x32_bf16(afr[kk], bfr[1][kk], acc1, 0, 0, 0);
      }
#pragma unroll
      for (int r = 0; r < 4; r++) {
        Gl[kh][mt * 16 + (l >> 4) * 4 + r][(l & 15)]      = acc0[r];
        Gl[kh][mt * 16 + (l >> 4) * 4 + r][16 + (l & 15)] = acc1[r];
      }
      Xs[tid] = myxp;

      if (k >= 2) {   // write output row for h_{k-1} (overlaps barrier wait)
        int row = dir ? (T_LEN - k + 1) : (k - 2);
        int ob = w >> 1, oc = (w & 1) * 256;
        u16 hv = __hip_atomic_load(hsrc + ob * 512 + oc + tid,
                                   __ATOMIC_RELAXED, __HIP_MEMORY_SCOPE_AGENT);
        out[((size_t)row * 32 + ob) * 1024 + dir * 512 + oc + tid] = bf2f(hv);
      }
      __syncthreads();                                 // barrier 2: gates ready

      float xi = bf2f(xsf[b_ * 32 + jj_]);
      float xf = bf2f(xsf[b_ * 32 + 8 + jj_]);
      float xg = bf2f(xsf[b_ * 32 + 16 + jj_]);
      float xo = bf2f(xsf[b_ * 32 + 24 + jj_]);
      float ai = Gl[0][b_][jj_]      + Gl[1][b_][jj_]      + xi;
      float af = Gl[0][b_][8 + jj_]  + Gl[1][b_][8 + jj_]  + xf;
      float ag = Gl[0][b_][16 + jj_] + Gl[1][b_][16 + jj_] + xg;
      float ao = Gl[0][b_][24 + jj_] + Gl[1][b_][24 + jj_] + xo;
      float si = sigm(ai), sf_ = sigm(af), sg = tanh_(ag), so = sigm(ao);
      c = sf_ * c + si * sg;
      float h = so * tanh_(c);
      ((u16*)Htmp)[tid] = f2bf(h);
      __syncthreads();                                 // barrier 3: Htmp ready

      if (wv == 0) {                                   // publish h_k + flag (release)
        const int cur = k & 1;
        u64 v = Htmp[l];
        u16* dstp = hb + (size_t)cur * (BATCH * HDIM) + (size_t)(l >> 1) * 512 + w * 8 + (l & 1) * 4;
        __hip_atomic_store((u64*)dstp, v, __ATOMIC_RELAXED, __HIP_MEMORY_SCOPE_AGENT);
        asm volatile("s_waitcnt vmcnt(0)" ::: "memory");
        if (l == 0)
          __hip_atomic_store(flg + w, (u32)k, __ATOMIC_RELAXED, __HIP_MEMORY_SCOPE_AGENT);
      }
    } else {
      // k == T+1: final output row from h_T
      int row = dir ? 0 : (T_LEN - 1);
      int ob = w >> 1, oc = (w & 1) * 256;
      u16 hv = __hip_atomic_load(hsrc + ob * 512 + oc + tid,
                                 __ATOMIC_RELAXED, __HIP_MEMORY_SCOPE_AGENT);
      out[((size_t)row * 32 + ob) * 1024 + dir * 512 + oc + tid] = bf2f(hv);
    }
  }
}

// ---------------------------------------------------------------------------------------
extern "C" void kernel_launch(void* const* d_in, const int* in_sizes, int n_in,
                              void* d_out, int out_size, void* d_ws, size_t ws_size,
                              hipStream_t stream) {
  if (ws_size < WS_NEED) return;  // workspace too small; bench will show failure

  const float* x     = (const float*)d_in[0];
  const float* h0_f  = (const float*)d_in[1];
  const float* c0_f  = (const float*)d_in[2];
  const float* h0_b  = (const float*)d_in[3];
  const float* c0_b  = (const float*)d_in[4];
  const float* Wih_f = (const float*)d_in[5];
  const float* Whh_f = (const float*)d_in[6];
  const float* b_f   = (const float*)d_in[7];
  const float* Wih_b = (const float*)d_in[8];
  const float* Whh_b = (const float*)d_in[9];
  const float* b_b   = (const float*)d_in[10];

  char* ws = (char*)d_ws;
  u16* xbf   = (u16*)(ws + XBF_OFF);
  u16* wihbf = (u16*)(ws + WIH_OFF);
  u16* whhbf = (u16*)(ws + WHH_OFF);
  u16* xpw   = (u16*)(ws + XP_OFF);
  u16* hbuf  = (u16*)(ws + HBUF_OFF);
  u32* flags = (u32*)(ws + FLG_OFF);

  prep_kernel<<<4096, 256, 0, stream>>>(
      (const float4*)x, (const float4*)Wih_f, (const float4*)Wih_b,
      (const float4*)Whh_f, (const float4*)Whh_b,
      (const float4*)h0_f, (const float4*)h0_b,
      (ushort4*)xbf, (ushort4*)wihbf, (ushort4*)whhbf, (ushort4*)hbuf, flags);

  dim3 g2(512, 16, 2);
  gemm_xp<<<g2, 256, 0, stream>>>(xbf, wihbf, b_f, b_b, xpw);

  lstm_scan<<<128, 256, 0, stream>>>(xpw, whhbf, c0_f, c0_b, hbuf, flags, (float*)d_out);
}